// Round 17
// baseline (3577.202 us; speedup 1.0000x reference)
//
#include <hip/hip_runtime.h>

typedef _Float16 f16;
using f16x8 = __attribute__((ext_vector_type(8))) _Float16;
using f32x4 = __attribute__((ext_vector_type(4))) float;

#define H 256
#define NM 2048

// async 16B global -> LDS (wave-uniform LDS base + lane*16)
__device__ __forceinline__ void gload_lds16(const f16* g, f16* lds)
{
    __builtin_amdgcn_global_load_lds(
        (const __attribute__((address_space(1))) void*)g,
        (__attribute__((address_space(3))) void*)lds, 16, 0, 0);
}

// ---------------------------------------------------------------------------
// r14-proven GEMM body. C[rows bm..bm+64)[256] = relu(
//   A1[.,K1r]@W1[256,128]^T + A2[.,256]@W2[256,256]^T + bias ).
// A2 and C may ALIAS (in-place): each block prefetches its A2 rows into
// registers up front and writes exactly the same rows in the epilogue
// (read-before-write per wave, rows disjoint across waves/blocks) -> no
// __restrict__ on A2/C. Bs[256][64] per 64-k window via global_load_lds
// with chunk^row XOR swizzle (r5-r16: SQ_LDS_BANK_CONFLICT == 0).
__device__ __forceinline__ void gemm_body(
    f16 (*Bs)[64],
    const float* __restrict__ A1, int lda1, int K1r,
    const f16*  __restrict__ W1,
    const f16* A2,
    const f16*  __restrict__ W2,
    const float* __restrict__ bias, f16* C,
    int bm, int Mend)
{
    const int tid  = threadIdx.x;
    const int wave = tid >> 6, lane = tid & 63;
    const int lrow = lane & 15;
    const int kg   = lane >> 4;
    const int swz  = lrow & 7;
    const int glr  = lane >> 3;
    const int gsc  = (lane & 7) ^ glr;

    const int  myrow = bm + wave * 16 + lrow;
    const bool rowok = myrow < Mend;

    f32x4 acc[16];
    #pragma unroll
    for (int n = 0; n < 16; ++n) acc[n] = (f32x4){0.f, 0.f, 0.f, 0.f};

    f16x8 af2[8];
    if (A2 != nullptr) {
        #pragma unroll
        for (int t = 0; t < 8; ++t) {
            if (rowok)
                af2[t] = *(const f16x8*)(A2 + (size_t)myrow * H + kg * 8 + t * 32);
            else {
                #pragma unroll
                for (int e = 0; e < 8; ++e) af2[t][e] = (f16)0.f;
            }
        }
    }

    auto stageB = [&](const f16* W, int ldw, int k0) {
        #pragma unroll
        for (int q = 0; q < 8; ++q)
            gload_lds16(W + (size_t)(wave * 64 + q * 8 + glr) * ldw + k0 + gsc * 8,
                        &Bs[wave * 64 + q * 8][0]);
    };

    auto mfma_win = [&](f16x8 a0, f16x8 a1) {
        #pragma unroll
        for (int ks = 0; ks < 2; ++ks) {
            const int cb = ((ks * 4 + kg) ^ swz) * 8;
            const f16x8 av = ks ? a1 : a0;
            #pragma unroll
            for (int n = 0; n < 16; ++n) {
                f16x8 b = *(const f16x8*)&Bs[n * 16 + lrow][cb];
                acc[n] = __builtin_amdgcn_mfma_f32_16x16x32_f16(av, b, acc[n], 0, 0, 0);
            }
        }
    };

    if (A1 != nullptr) {
        #pragma unroll
        for (int w = 0; w < 2; ++w) {
            f16x8 a[2];
            #pragma unroll
            for (int c = 0; c < 2; ++c) {
                const int k0 = (w * 8 + c * 4 + kg) * 8;
                const float* sp = A1 + (size_t)myrow * lda1 + k0;
                f16 tmp[8];
                #pragma unroll
                for (int i = 0; i < 8; i += 2) {
                    float x = 0.f, y = 0.f;
                    if (rowok) {
                        if (k0 + i + 1 < K1r) { float2 v = *(const float2*)(sp + i); x = v.x; y = v.y; }
                        else if (k0 + i < K1r) { x = sp[i]; }
                    }
                    tmp[i] = (f16)x; tmp[i + 1] = (f16)y;
                }
                a[c] = *(const f16x8*)tmp;
            }
            stageB(W1, 128, w * 64);
            __syncthreads();
            mfma_win(a[0], a[1]);
            __syncthreads();
        }
    }

    if (A2 != nullptr) {
        #pragma unroll
        for (int w = 0; w < 4; ++w) {
            stageB(W2, H, w * 64);
            __syncthreads();
            mfma_win(af2[w * 2], af2[w * 2 + 1]);
            __syncthreads();
        }
    }

    // epilogue: C/D layout col=lane&15, row=kg*4+reg (validated rounds 3-16)
    #pragma unroll
    for (int n = 0; n < 16; ++n) {
        const int gc = n * 16 + lrow;
        const float bv = bias ? bias[gc] : 0.f;
        #pragma unroll
        for (int r = 0; r < 4; ++r) {
            const int gr = bm + wave * 16 + kg * 4 + r;
            if (gr < Mend) C[(size_t)gr * H + gc] = (f16)fmaxf(acc[n][r] + bv, 0.f);
        }
    }
}

// gather inner: dst[row,:] = sum_{j<10} src[idx[row][j],:]  (32 lanes x 16B)
__device__ __forceinline__ void gather_body(
    const f16* __restrict__ src, const int* __restrict__ idx,
    f16* __restrict__ dst, int row, int lane)
{
    const int* ip = idx + (size_t)row * 10;
    float s[8] = {};
    #pragma unroll
    for (int j = 0; j < 10; ++j) {
        int r = ip[j];
        float4 v = *((const float4*)(src + (size_t)r * H) + lane);
        const f16* pb = (const f16*)&v;
        #pragma unroll
        for (int e = 0; e < 8; ++e) s[e] += (float)pb[e];
    }
    f16 o[8];
    #pragma unroll
    for (int e = 0; e < 8; ++e) o[e] = (f16)s[e];
    *((float4*)(dst + (size_t)row * H) + lane) = *(const float4*)o;
}

// ---------------------------------------------------------------------------
__global__ __launch_bounds__(256, 4) void gemm_dense(
    const float* __restrict__ A1, int lda1, int K1r,
    const f16*  __restrict__ W1,
    const f16* A2,
    const f16*  __restrict__ W2,
    const float* __restrict__ bias, f16* C,
    int row0, int Mend)
{
    __shared__ f16 Bs[256][64];
    gemm_body(Bs, A1, lda1, K1r, W1, A2, W2, bias, C, row0 + blockIdx.x * 64, Mend);
}

__global__ __launch_bounds__(256) void gather_sum10(
    const f16* __restrict__ src, const int* __restrict__ idx,
    f16* __restrict__ dst, int row0, int rend)
{
    int row = row0 + blockIdx.x * 8 + (threadIdx.x >> 5);
    if (row < rend) gather_body(src, idx, dst, row, threadIdx.x & 31);
}

// Combined dispatch: 1 GEMM block every `period` blocks, rest gather blocks.
// GEMM: chunk rows [g_row0, g_Mend) of Y, IN PLACE. Gather: rows [a_row0,
// a_end) of Y (next chunk). Disjoint regions; gather source `gsrc` untouched
// by the GEMM -> race-free.
__global__ __launch_bounds__(256, 4) void fused_step(
    const float* __restrict__ A1, int lda1, int K1r,
    const f16*  __restrict__ W1,
    const f16* A2,
    const f16*  __restrict__ W2,
    const float* __restrict__ bias, f16* C,
    int g_row0, int g_Mend, int nge, int period,
    const f16* __restrict__ gsrc, const int* __restrict__ gidx,
    f16* __restrict__ gdst, int a_row0, int a_end)
{
    __shared__ f16 Bs[256][64];
    const int bid = blockIdx.x;
    const int q = bid / period, r = bid % period;
    if (r == 0 && q < nge) {
        gemm_body(Bs, A1, lda1, K1r, W1, A2, W2, bias, C, g_row0 + q * 64, g_Mend);
    } else {
        int ab = bid - min(q + 1, nge);
        int row = a_row0 + ab * 8 + (threadIdx.x >> 5);
        if (row < a_end) gather_body(gsrc, gidx, gdst, row, threadIdx.x & 31);
    }
}

// ---------------------------------------------------------------------------
__global__ __launch_bounds__(256) void convert_w(
    const float* __restrict__ src, int lds_, int koff, int kvalid,
    f16* __restrict__ dst, int Kd)
{
    int n = blockIdx.x;
    for (int k = threadIdx.x; k < Kd; k += 256) {
        float v = (k < kvalid) ? src[(size_t)n * lds_ + koff + k] : 0.f;
        dst[(size_t)n * Kd + k] = (f16)v;
    }
}

__global__ __launch_bounds__(256) void segsum(
    const f16* __restrict__ atom_h, const int* __restrict__ mol_idx,
    float* __restrict__ mol_h, int n_atoms)
{
    int m = blockIdx.x;
    int lo = 0, hi = n_atoms;
    while (lo < hi) { int mid = (lo + hi) >> 1; if (mol_idx[mid] < m) lo = mid + 1; else hi = mid; }
    int start = lo;
    hi = n_atoms;
    while (lo < hi) { int mid = (lo + hi) >> 1; if (mol_idx[mid] < m + 1) lo = mid + 1; else hi = mid; }
    int end = lo;
    int c = threadIdx.x;
    float s = 0.f;
    for (int a = start; a < end; ++a) s += (float)atom_h[(size_t)a * H + c];
    mol_h[(size_t)m * H + c] = s;
}

__global__ __launch_bounds__(256) void diff_kernel(
    const float* __restrict__ a, const float* __restrict__ b,
    f16* __restrict__ c, int n)
{
    int i = blockIdx.x * 256 + threadIdx.x;
    if (i < n) c[i] = (f16)(a[i] - b[i]);
}

__global__ __launch_bounds__(256) void final_dot(
    const f16* __restrict__ rxn, const float* __restrict__ Wro,
    const float* __restrict__ bro, float* __restrict__ out)
{
    int m = blockIdx.x;
    int t = threadIdx.x;
    float v = (float)rxn[(size_t)m * H + t] * Wro[t];
    #pragma unroll
    for (int off = 32; off; off >>= 1) v += __shfl_down(v, off, 64);
    __shared__ float red[4];
    if ((t & 63) == 0) red[t >> 6] = v;
    __syncthreads();
    if (t == 0) out[m] = red[0] + red[1] + red[2] + red[3] + bro[0];
}

// ---------------------------------------------------------------------------
// One stage: Y = gather10(src_buf, idx) over n rows into ybuf, then
// ybuf = relu(A1@W1^T + Y@W2^T + bias) IN PLACE, chunk-pipelined:
//   g(c0); [G(c0) || g(c1)]; [G(c1) || g(c2)]; [G(c2) || g(c3)]; G(c3)
static void stage_pipelined(const float* A1, int lda1, int K1r, const f16* W1,
                            const f16* src_buf, const int* idx, const f16* W2,
                            const float* bias, f16* ybuf, int n,
                            hipStream_t stream)
{
    const int NC = 4;
    const int CS = (((n + NC - 1) / NC + 63) / 64) * 64;
    auto lo = [&](int c) { return min(c * CS, n); };
    auto hi = [&](int c) { return min((c + 1) * CS, n); };

    // prologue gather: chunk 0
    gather_sum10<<<(hi(0) - lo(0) + 7) / 8, 256, 0, stream>>>(src_buf, idx, ybuf, lo(0), hi(0));

    for (int c = 0; c < NC; ++c) {
        const int gs = lo(c), ge = hi(c);            // GEMM chunk
        const int as = lo(c + 1), ae = hi(c + 1);    // gather chunk (next)
        const int nge = (ge - gs + 63) / 64;
        if (ae > as) {
            const int nga = (ae - as + 7) / 8;
            const int tot = nge + nga;
            const int per = tot / nge > 0 ? tot / nge : 1;
            fused_step<<<tot, 256, 0, stream>>>(
                A1, lda1, K1r, W1, ybuf, W2, bias, ybuf,
                gs, ge, nge, per, src_buf, idx, ybuf, as, ae);
        } else {
            gemm_dense<<<nge, 256, 0, stream>>>(
                A1, lda1, K1r, W1, ybuf, W2, bias, ybuf, gs, ge);
        }
    }
}

static void run_graph(const float* fatoms, const float* fbonds, const int* agraph,
                      const int* bgraph, const int* mol_idx,
                      const f16* Wi16, const f16* Wh16, const f16* Wo1, const f16* Wo2,
                      const float* bo,
                      f16* bufA, f16* bufB, float* molh,
                      int n_atoms, int n_bonds, hipStream_t stream)
{
    const float* nul_f = nullptr;
    const f16*   nul_h = nullptr;

    // msg0 = relu(fbonds @ Wi^T)
    gemm_dense<<<(n_bonds + 63) / 64, 256, 0, stream>>>(
        fbonds, 88, 88, Wi16, nul_h, nul_h, nul_f, bufA, 0, n_bonds);
    f16* cur = bufA; f16* nxt = bufB;

    for (int it = 0; it < 3; ++it) {
        // nxt = relu(fbonds@Wi^T + gather10(cur,bgraph)@Wh^T)  (pipelined, in-place on nxt)
        stage_pipelined(fbonds, 88, 88, Wi16, cur, bgraph, Wh16,
                        nul_f, nxt, n_bonds, stream);
        f16* t = cur; cur = nxt; nxt = t;
    }
    // nxt = relu(fatoms@Wo1^T + gather10(cur,agraph)@Wo2^T + bo)   (atom rows)
    stage_pipelined(fatoms, 82, 82, Wo1, cur, agraph, Wo2,
                    bo, nxt, n_atoms, stream);
    segsum<<<NM, 256, 0, stream>>>(nxt, mol_idx, molh, n_atoms);
}

extern "C" void kernel_launch(void* const* d_in, const int* in_sizes, int n_in,
                              void* d_out, int out_size, void* d_ws, size_t ws_size,
                              hipStream_t stream)
{
    const float* fatoms_src = (const float*)d_in[0];
    const float* fbonds_src = (const float*)d_in[1];
    const int*   agraph_src = (const int*)d_in[2];
    const int*   bgraph_src = (const int*)d_in[3];
    const int*   mol_idx_src= (const int*)d_in[4];
    const float* fatoms_tgt = (const float*)d_in[5];
    const float* fbonds_tgt = (const float*)d_in[6];
    const int*   agraph_tgt = (const int*)d_in[7];
    const int*   bgraph_tgt = (const int*)d_in[8];
    const int*   mol_idx_tgt= (const int*)d_in[9];
    const float* Wi_s = (const float*)d_in[10];
    const float* Wh_s = (const float*)d_in[11];
    const float* Wo_s = (const float*)d_in[12];
    const float* bo_s = (const float*)d_in[13];
    const float* Wi_t = (const float*)d_in[14];
    const float* Wh_t = (const float*)d_in[15];
    const float* Wo_t = (const float*)d_in[16];
    const float* bo_t = (const float*)d_in[17];
    const float* Wrh  = (const float*)d_in[18];
    const float* brh  = (const float*)d_in[19];
    const float* Wro  = (const float*)d_in[20];
    const float* bro  = (const float*)d_in[21];

    const int n_atoms = in_sizes[0] / 82;
    const int n_bonds = in_sizes[1] / 88;

    // ---- workspace layout (~212 MB, same proven footprint) ----
    char* ws = (char*)d_ws;
    size_t off = 0;
    auto alloc = [&](size_t bytes) { size_t o = off; off = (off + bytes + 255) & ~(size_t)255; return o; };
    f16*   bufA = (f16*)(ws + alloc((size_t)n_bonds * H * 2));
    f16*   bufB = (f16*)(ws + alloc((size_t)n_bonds * H * 2));
    float* molS = (float*)(ws + alloc((size_t)NM * H * 4));
    float* molT = (float*)(ws + alloc((size_t)NM * H * 4));
    f16*   dbuf = (f16*)(ws + alloc((size_t)NM * H * 2));
    f16*   rxn  = (f16*)(ws + alloc((size_t)NM * H * 2));
    f16* Wi16_s = (f16*)(ws + alloc(256 * 128 * 2));
    f16* Wh16_s = (f16*)(ws + alloc(256 * 256 * 2));
    f16* Wo1_s  = (f16*)(ws + alloc(256 * 128 * 2));
    f16* Wo2_s  = (f16*)(ws + alloc(256 * 256 * 2));
    f16* Wi16_t = (f16*)(ws + alloc(256 * 128 * 2));
    f16* Wh16_t = (f16*)(ws + alloc(256 * 256 * 2));
    f16* Wo1_t  = (f16*)(ws + alloc(256 * 128 * 2));
    f16* Wo2_t  = (f16*)(ws + alloc(256 * 256 * 2));
    f16* Wrh16  = (f16*)(ws + alloc(256 * 256 * 2));

    convert_w<<<256, 256, 0, stream>>>(Wi_s,  88,  0,  88, Wi16_s, 128);
    convert_w<<<256, 256, 0, stream>>>(Wh_s, 256,  0, 256, Wh16_s, 256);
    convert_w<<<256, 256, 0, stream>>>(Wo_s, 338,  0,  82, Wo1_s, 128);
    convert_w<<<256, 256, 0, stream>>>(Wo_s, 338, 82, 256, Wo2_s, 256);
    convert_w<<<256, 256, 0, stream>>>(Wi_t,  88,  0,  88, Wi16_t, 128);
    convert_w<<<256, 256, 0, stream>>>(Wh_t, 256,  0, 256, Wh16_t, 256);
    convert_w<<<256, 256, 0, stream>>>(Wo_t, 338,  0,  82, Wo1_t, 128);
    convert_w<<<256, 256, 0, stream>>>(Wo_t, 338, 82, 256, Wo2_t, 256);
    convert_w<<<256, 256, 0, stream>>>(Wrh, 256,  0, 256, Wrh16, 256);

    run_graph(fatoms_src, fbonds_src, agraph_src, bgraph_src, mol_idx_src,
              Wi16_s, Wh16_s, Wo1_s, Wo2_s, bo_s,
              bufA, bufB, molS, n_atoms, n_bonds, stream);
    run_graph(fatoms_tgt, fbonds_tgt, agraph_tgt, bgraph_tgt, mol_idx_tgt,
              Wi16_t, Wh16_t, Wo1_t, Wo2_t, bo_t,
              bufA, bufB, molT, n_atoms, n_bonds, stream);

    diff_kernel<<<(NM * H + 255) / 256, 256, 0, stream>>>(molT, molS, dbuf, NM * H);
    gemm_dense<<<NM / 64, 256, 0, stream>>>(
        (const float*)nullptr, 0, 0, (const f16*)nullptr, dbuf, Wrh16,
        brh, rxn, 0, NM);
    final_dot<<<NM, 256, 0, stream>>>(rxn, Wro, bro, (float*)d_out);
}

// Round 18
// 2286.048 us; speedup vs baseline: 1.5648x; 1.5648x over previous
//
#include <hip/hip_runtime.h>

typedef _Float16 f16;
using f16x8 = __attribute__((ext_vector_type(8))) _Float16;
using f32x4 = __attribute__((ext_vector_type(4))) float;

#define H 256
#define NM 2048

// async 16B global -> LDS (wave-uniform LDS base + lane*16)
__device__ __forceinline__ void gload_lds16(const f16* g, f16* lds)
{
    __builtin_amdgcn_global_load_lds(
        (const __attribute__((address_space(1))) void*)g,
        (__attribute__((address_space(3))) void*)lds, 16, 0, 0);
}

// ---------------------------------------------------------------------------
// C[M,256] = relu( [P0: A1[M,K1r]@W1[256,128]^T] + [P1: A2[M,256]@W2[256,256]^T] + bias )
// Block = 64 rows, 4 waves; wave w owns rows [bm+16w, +16) x all 256 cols.
// A fully register-resident (prefetched up front). Weights staged per window
// = (64-k) x (128-col half): Bs[2][128][64] double-buffered (32 KB total ->
// occupancy preserved vs r16), 2-phase schedule: stage(w+1) issued BEFORE
// compute(w), one barrier per window -> stage latency hides under 16 MFMAs.
// Proven 128B-row chunk^row XOR swizzle (r5-r17: SQ_LDS_BANK_CONFLICT == 0).
template<bool P0, bool P1>
__global__ __launch_bounds__(256, 4) void gemm_dense(
    const float* __restrict__ A1, int lda1, int K1r,
    const f16*  __restrict__ W1,
    const f16*  __restrict__ A2,
    const f16*  __restrict__ W2,
    const float* __restrict__ bias, f16* __restrict__ C,
    int row0, int Mend)
{
    __shared__ f16 Bs[2][128][64];
    constexpr int NW = (P0 ? 4 : 0) + (P1 ? 8 : 0);   // (k-windows) x (n-halves)

    const int bm   = row0 + blockIdx.x * 64;
    const int tid  = threadIdx.x;
    const int wave = tid >> 6, lane = tid & 63;
    const int lrow = lane & 15;
    const int kg   = lane >> 4;
    const int swz  = lrow & 7;
    const int glr  = lane >> 3;
    const int gsc  = (lane & 7) ^ glr;      // swizzled source chunk

    const int  myrow = bm + wave * 16 + lrow;
    const bool rowok = myrow < Mend;

    f32x4 acc[16];
    #pragma unroll
    for (int n = 0; n < 16; ++n) acc[n] = (f32x4){0.f, 0.f, 0.f, 0.f};

    // ---- prefetch ALL A fragments into registers ----
    f16x8 af1[2][2];    // P0: [k-window][ks]
    f16x8 af2[4][2];    // P1: [k-window][ks]
    if (P1) {
        #pragma unroll
        for (int t = 0; t < 8; ++t) {
            if (rowok)
                af2[t >> 1][t & 1] = *(const f16x8*)(A2 + (size_t)myrow * H + t * 32 + kg * 8);
            else {
                #pragma unroll
                for (int e = 0; e < 8; ++e) af2[t >> 1][t & 1][e] = (f16)0.f;
            }
        }
    }
    if (P0) {
        #pragma unroll
        for (int kw = 0; kw < 2; ++kw) {
            #pragma unroll
            for (int ks = 0; ks < 2; ++ks) {
                const int k0 = kw * 64 + ks * 32 + kg * 8;
                const float* sp = A1 + (size_t)myrow * lda1 + k0;
                f16 tmp[8];
                #pragma unroll
                for (int i = 0; i < 8; i += 2) {
                    float x = 0.f, y = 0.f;
                    if (rowok) {
                        if (k0 + i + 1 < K1r) { float2 v = *(const float2*)(sp + i); x = v.x; y = v.y; }
                        else if (k0 + i < K1r) { x = sp[i]; }
                    }
                    tmp[i] = (f16)x; tmp[i + 1] = (f16)y;
                }
                af1[kw][ks] = *(const f16x8*)tmp;
            }
        }
    }

    // window w: pass0 (w<4 when P0) -> W1[nh*128 rows][k], else W2.
    // wp = in-pass index; k0 = (wp>>1)*64; nh = wp&1.
    auto stage_w = [&](int w, int buf) {
        const bool p0 = P0 && (w < 4);
        const f16* W  = p0 ? W1 : W2;
        const int ldw = p0 ? 128 : 256;
        const int wp  = p0 ? w : (P0 ? w - 4 : w);
        const int k0  = (wp >> 1) * 64;
        const int nh  = wp & 1;
        #pragma unroll
        for (int q = 0; q < 4; ++q)
            gload_lds16(W + (size_t)(nh * 128 + wave * 32 + q * 8 + glr) * ldw + k0 + gsc * 8,
                        &Bs[buf][wave * 32 + q * 8][0]);
    };

    auto mfma_w = [&](int w, int buf) {
        const bool p0 = P0 && (w < 4);
        const int wp  = p0 ? w : (P0 ? w - 4 : w);
        const int nh  = wp & 1;
        #pragma unroll
        for (int ks = 0; ks < 2; ++ks) {
            const int cb = ((ks * 4 + kg) ^ swz) * 8;
            const f16x8 a = p0 ? af1[wp >> 1][ks] : af2[wp >> 1][ks];
            #pragma unroll
            for (int j = 0; j < 8; ++j) {
                f16x8 b = *(const f16x8*)&Bs[buf][j * 16 + lrow][cb];
                acc[nh * 8 + j] = __builtin_amdgcn_mfma_f32_16x16x32_f16(a, b, acc[nh * 8 + j], 0, 0, 0);
            }
        }
    };

    stage_w(0, 0);
    __syncthreads();
    #pragma unroll
    for (int w = 0; w < NW; ++w) {
        if (w + 1 < NW) stage_w(w + 1, (w + 1) & 1);  // issue next stage FIRST
        mfma_w(w, w & 1);                             // compute current
        __syncthreads();                              // drains stage(w+1), mostly done
    }

    // epilogue: C/D layout col=lane&15, row=kg*4+reg (validated rounds 3-17)
    #pragma unroll
    for (int n = 0; n < 16; ++n) {
        const int gc = n * 16 + lrow;
        const float bv = bias ? bias[gc] : 0.f;
        #pragma unroll
        for (int r = 0; r < 4; ++r) {
            const int gr = bm + wave * 16 + kg * 4 + r;
            if (gr < Mend) C[(size_t)gr * H + gc] = (f16)fmaxf(acc[n][r] + bv, 0.f);
        }
    }
}

// ---------------------------------------------------------------------------
// dst[i,:] = sum_{j<10} src[idx[i,j], :]  (row = 512B = 32 lanes x 16B)
__global__ __launch_bounds__(256) void gather_sum10(
    const f16* __restrict__ src, const int* __restrict__ idx,
    f16* __restrict__ dst, int n_rows)
{
    int row  = blockIdx.x * 8 + (threadIdx.x >> 5);
    int lane = threadIdx.x & 31;
    if (row >= n_rows) return;
    const int* ip = idx + (size_t)row * 10;
    float s[8] = {};
    #pragma unroll
    for (int j = 0; j < 10; ++j) {
        int r = ip[j];
        float4 v = *((const float4*)(src + (size_t)r * H) + lane);
        const f16* pb = (const f16*)&v;
        #pragma unroll
        for (int e = 0; e < 8; ++e) s[e] += (float)pb[e];
    }
    f16 o[8];
    #pragma unroll
    for (int e = 0; e < 8; ++e) o[e] = (f16)s[e];
    *((float4*)(dst + (size_t)row * H) + lane) = *(const float4*)o;
}

// ---------------------------------------------------------------------------
__global__ __launch_bounds__(256) void convert_w(
    const float* __restrict__ src, int lds_, int koff, int kvalid,
    f16* __restrict__ dst, int Kd)
{
    int n = blockIdx.x;
    for (int k = threadIdx.x; k < Kd; k += 256) {
        float v = (k < kvalid) ? src[(size_t)n * lds_ + koff + k] : 0.f;
        dst[(size_t)n * Kd + k] = (f16)v;
    }
}

__global__ __launch_bounds__(256) void segsum(
    const f16* __restrict__ atom_h, const int* __restrict__ mol_idx,
    float* __restrict__ mol_h, int n_atoms)
{
    int m = blockIdx.x;
    int lo = 0, hi = n_atoms;
    while (lo < hi) { int mid = (lo + hi) >> 1; if (mol_idx[mid] < m) lo = mid + 1; else hi = mid; }
    int start = lo;
    hi = n_atoms;
    while (lo < hi) { int mid = (lo + hi) >> 1; if (mol_idx[mid] < m + 1) lo = mid + 1; else hi = mid; }
    int end = lo;
    int c = threadIdx.x;
    float s = 0.f;
    for (int a = start; a < end; ++a) s += (float)atom_h[(size_t)a * H + c];
    mol_h[(size_t)m * H + c] = s;
}

__global__ __launch_bounds__(256) void diff_kernel(
    const float* __restrict__ a, const float* __restrict__ b,
    f16* __restrict__ c, int n)
{
    int i = blockIdx.x * 256 + threadIdx.x;
    if (i < n) c[i] = (f16)(a[i] - b[i]);
}

__global__ __launch_bounds__(256) void final_dot(
    const f16* __restrict__ rxn, const float* __restrict__ Wro,
    const float* __restrict__ bro, float* __restrict__ out)
{
    int m = blockIdx.x;
    int t = threadIdx.x;
    float v = (float)rxn[(size_t)m * H + t] * Wro[t];
    #pragma unroll
    for (int off = 32; off; off >>= 1) v += __shfl_down(v, off, 64);
    __shared__ float red[4];
    if ((t & 63) == 0) red[t >> 6] = v;
    __syncthreads();
    if (t == 0) out[m] = red[0] + red[1] + red[2] + red[3] + bro[0];
}

// ---------------------------------------------------------------------------
static void run_graph(const float* fatoms, const float* fbonds, const int* agraph,
                      const int* bgraph, const int* mol_idx,
                      const f16* Wi16, const f16* Wh16, const f16* Wo1, const f16* Wo2,
                      const float* bo,
                      f16* bufA, f16* bufB, float* molh,
                      int n_atoms, int n_bonds, hipStream_t stream)
{
    const float* nul_f = nullptr;
    const f16*   nul_h = nullptr;

    // msg0 = relu(fbonds @ Wi^T)
    gemm_dense<true, false><<<(n_bonds + 63) / 64, 256, 0, stream>>>(
        fbonds, 88, 88, Wi16, nul_h, nul_h, nul_f, bufA, 0, n_bonds);
    f16* cur = bufA; f16* nxt = bufB;

    for (int it = 0; it < 3; ++it) {
        // Y = gather10(msg, bgraph)            (full grid, L2/L3-served)
        gather_sum10<<<(n_bonds + 7) / 8, 256, 0, stream>>>(cur, bgraph, nxt, n_bonds);
        // msg' = relu(fbonds@Wi^T + Y@Wh^T)    (full grid, pipelined windows)
        gemm_dense<true, true><<<(n_bonds + 63) / 64, 256, 0, stream>>>(
            fbonds, 88, 88, Wi16, nxt, Wh16, nul_f, cur, 0, n_bonds);
    }
    // Ya = gather10(msg, agraph)
    gather_sum10<<<(n_atoms + 7) / 8, 256, 0, stream>>>(cur, agraph, nxt, n_atoms);
    // atom_h = relu(fatoms@Wo1^T + Ya@Wo2^T + bo)   (-> cur; reads nxt+fatoms)
    gemm_dense<true, true><<<(n_atoms + 63) / 64, 256, 0, stream>>>(
        fatoms, 82, 82, Wo1, nxt, Wo2, bo, cur, 0, n_atoms);
    segsum<<<NM, 256, 0, stream>>>(cur, mol_idx, molh, n_atoms);
}

extern "C" void kernel_launch(void* const* d_in, const int* in_sizes, int n_in,
                              void* d_out, int out_size, void* d_ws, size_t ws_size,
                              hipStream_t stream)
{
    const float* fatoms_src = (const float*)d_in[0];
    const float* fbonds_src = (const float*)d_in[1];
    const int*   agraph_src = (const int*)d_in[2];
    const int*   bgraph_src = (const int*)d_in[3];
    const int*   mol_idx_src= (const int*)d_in[4];
    const float* fatoms_tgt = (const float*)d_in[5];
    const float* fbonds_tgt = (const float*)d_in[6];
    const int*   agraph_tgt = (const int*)d_in[7];
    const int*   bgraph_tgt = (const int*)d_in[8];
    const int*   mol_idx_tgt= (const int*)d_in[9];
    const float* Wi_s = (const float*)d_in[10];
    const float* Wh_s = (const float*)d_in[11];
    const float* Wo_s = (const float*)d_in[12];
    const float* bo_s = (const float*)d_in[13];
    const float* Wi_t = (const float*)d_in[14];
    const float* Wh_t = (const float*)d_in[15];
    const float* Wo_t = (const float*)d_in[16];
    const float* bo_t = (const float*)d_in[17];
    const float* Wrh  = (const float*)d_in[18];
    const float* brh  = (const float*)d_in[19];
    const float* Wro  = (const float*)d_in[20];
    const float* bro  = (const float*)d_in[21];

    const int n_atoms = in_sizes[0] / 82;
    const int n_bonds = in_sizes[1] / 88;

    // ---- workspace layout (~212 MB, same proven footprint) ----
    char* ws = (char*)d_ws;
    size_t off = 0;
    auto alloc = [&](size_t bytes) { size_t o = off; off = (off + bytes + 255) & ~(size_t)255; return o; };
    f16*   bufA = (f16*)(ws + alloc((size_t)n_bonds * H * 2));
    f16*   bufB = (f16*)(ws + alloc((size_t)n_bonds * H * 2));
    float* molS = (float*)(ws + alloc((size_t)NM * H * 4));
    float* molT = (float*)(ws + alloc((size_t)NM * H * 4));
    f16*   dbuf = (f16*)(ws + alloc((size_t)NM * H * 2));
    f16*   rxn  = (f16*)(ws + alloc((size_t)NM * H * 2));
    f16* Wi16_s = (f16*)(ws + alloc(256 * 128 * 2));
    f16* Wh16_s = (f16*)(ws + alloc(256 * 256 * 2));
    f16* Wo1_s  = (f16*)(ws + alloc(256 * 128 * 2));
    f16* Wo2_s  = (f16*)(ws + alloc(256 * 256 * 2));
    f16* Wi16_t = (f16*)(ws + alloc(256 * 128 * 2));
    f16* Wh16_t = (f16*)(ws + alloc(256 * 256 * 2));
    f16* Wo1_t  = (f16*)(ws + alloc(256 * 128 * 2));
    f16* Wo2_t  = (f16*)(ws + alloc(256 * 256 * 2));
    f16* Wrh16  = (f16*)(ws + alloc(256 * 256 * 2));

    convert_w<<<256, 256, 0, stream>>>(Wi_s,  88,  0,  88, Wi16_s, 128);
    convert_w<<<256, 256, 0, stream>>>(Wh_s, 256,  0, 256, Wh16_s, 256);
    convert_w<<<256, 256, 0, stream>>>(Wo_s, 338,  0,  82, Wo1_s, 128);
    convert_w<<<256, 256, 0, stream>>>(Wo_s, 338, 82, 256, Wo2_s, 256);
    convert_w<<<256, 256, 0, stream>>>(Wi_t,  88,  0,  88, Wi16_t, 128);
    convert_w<<<256, 256, 0, stream>>>(Wh_t, 256,  0, 256, Wh16_t, 256);
    convert_w<<<256, 256, 0, stream>>>(Wo_t, 338,  0,  82, Wo1_t, 128);
    convert_w<<<256, 256, 0, stream>>>(Wo_t, 338, 82, 256, Wo2_t, 256);
    convert_w<<<256, 256, 0, stream>>>(Wrh, 256,  0, 256, Wrh16, 256);

    run_graph(fatoms_src, fbonds_src, agraph_src, bgraph_src, mol_idx_src,
              Wi16_s, Wh16_s, Wo1_s, Wo2_s, bo_s,
              bufA, bufB, molS, n_atoms, n_bonds, stream);
    run_graph(fatoms_tgt, fbonds_tgt, agraph_tgt, bgraph_tgt, mol_idx_tgt,
              Wi16_t, Wh16_t, Wo1_t, Wo2_t, bo_t,
              bufA, bufB, molT, n_atoms, n_bonds, stream);

    diff_kernel<<<(NM * H + 255) / 256, 256, 0, stream>>>(molT, molS, dbuf, NM * H);
    // rxn_h = relu(diff @ Wrh^T + brh)
    gemm_dense<false, true><<<NM / 64, 256, 0, stream>>>(
        (const float*)nullptr, 0, 0, (const f16*)nullptr, dbuf, Wrh16,
        brh, rxn, 0, NM);
    final_dot<<<NM, 256, 0, stream>>>(rxn, Wro, bro, (float*)d_out);
}